// Round 8
// baseline (287.119 us; speedup 1.0000x reference)
//
#include <hip/hip_runtime.h>

// out[b,h,t,f] = sum_{r=0..64} a[b,h,t,r] * v[b,h, t+r-32, f]  (zero-padded in t)
// B=8 H=16 T=4096 F=64 R=65, fp32 in/out. bf16 MFMA (absmax 0.25 vs thr 1.0).
//
// Round 8: REAL pipelining. __syncthreads() emits s_waitcnt vmcnt(0) -> every
// round-6/7 "prefetch" was drained at the next barrier (guide §5 m97 analysis).
// Now: raw s_barrier with lgkmcnt(0)-only waits (LDS ordering needs no vmcnt),
// so global loads stay in flight across barriers (T3/T4), plus depth-2 prefetch
// with two static register sets (A/B, fully unrolled 4-tile schedule, rule #20).
// Ring-buffered sv kept (steady tiles load only 64 new v rows).

#define TT 4096
#define RRR 65
#define FF 64
#define TILE 64
#define SA_S 100     // bf16 row stride
#define SV_S 132     // bf16 row stride; ring occupies c in [0,128)
#define NTPB 4       // tiles per block -> 16 blocks per (b,h), grid 2048
#define RM 127       // ring mask

typedef short bf16x8 __attribute__((ext_vector_type(8)));
typedef float f32x16 __attribute__((ext_vector_type(16)));

__device__ __forceinline__ unsigned short f2bf(float x) {
    unsigned int u = __float_as_uint(x);
    u += 0x7fff + ((u >> 16) & 1);            // RNE
    return (unsigned short)(u >> 16);
}
__device__ __forceinline__ unsigned pk2(float lo, float hi) {
    return (unsigned)f2bf(lo) | ((unsigned)f2bf(hi) << 16);
}

// Barrier with LDS-only drain: global loads stay in flight (no vmcnt!).
#define BAR() do {                                                             \
    asm volatile("s_waitcnt lgkmcnt(0)" ::: "memory");                         \
    __builtin_amdgcn_sched_barrier(0);                                         \
    __builtin_amdgcn_s_barrier();                                              \
    __builtin_amdgcn_sched_barrier(0);                                         \
} while (0)

__global__ __launch_bounds__(256, 5)
void unfold_mfma(const float* __restrict__ a, const float* __restrict__ v,
                 float* __restrict__ out) {
    __shared__ __align__(16) unsigned short sa[TILE * SA_S];  // 12800 B
    __shared__ __align__(16) unsigned short sv[FF * SV_S];    // 16896 B

    const int tid = threadIdx.x;
    const int f   = tid & 63;
    const int wv  = tid >> 6;
    const int n   = f & 31;
    const int hi  = f >> 5;
    const int wr  = wv >> 1;
    const int wc  = wv & 1;
    const int Rw  = 32 * wr + n;

    const int bh = blockIdx.x >> 4;                 // 16 blocks per (b,h)
    const int T0 = (blockIdx.x & 15) << 8;          // 256-row span per block

    const float* vsl = v + (size_t)bh * TT * FF;
    const size_t obase = (size_t)bh * TT * FF;

    // ---- one-time zero-prefill of sa (band complement stays 0 across tiles) ----
    {
        uint4 z = make_uint4(0, 0, 0, 0);
        uint4* sp = (uint4*)sa;
        #pragma unroll
        for (int it = 0; it < 4; ++it) {
            int lin = tid + it * 256;
            if (lin < (TILE * SA_S) / 8) sp[lin] = z;
        }
    }

#define ISSUE_A_(AQ, AE, TROW) do {                                            \
    const float* arow_ = a + ((size_t)bh * TT + (TROW)) * RRR;                 \
    _Pragma("unroll")                                                          \
    for (int it = 0; it < 4; ++it) {                                           \
        int lin = tid + it * 256;                                              \
        if (lin < TILE * 15) {                                                 \
            int R = lin / 15, j = lin - R * 15;                                \
            int r0 = (4 - (R & 3)) & 3;                                        \
            AQ[it] = *(const float4*)(arow_ + (size_t)R * RRR + r0 + 4 * j);   \
        }                                                                      \
    }                                                                          \
    _Pragma("unroll")                                                          \
    for (int it = 0; it < 2; ++it) {                                           \
        int lin = tid + it * 256;                                              \
        if (lin < TILE * 5) {                                                  \
            int R = lin / 5, e = lin - R * 5;                                  \
            int r0 = (4 - (R & 3)) & 3;                                        \
            int r = (e < r0) ? e : 60 + e;                                     \
            AE[it] = arow_[(size_t)R * RRR + r];                               \
        }                                                                      \
    }                                                                          \
} while (0)

    // load 64 rows [S0, S0+64); wave wv takes [S0+16wv, +16)
#define ISSUE_V_(VV, S0) do {                                                  \
    const int gb_ = (S0) + 16 * wv;                                            \
    if ((S0) + 64 <= TT) {                                                     \
        _Pragma("unroll")                                                      \
        for (int it = 0; it < 4; ++it)                                         \
            _Pragma("unroll")                                                  \
            for (int j = 0; j < 4; ++j)                                        \
                VV[it][j] = vsl[(size_t)(gb_ + 4 * it + j) * FF + f];          \
    } else {                                                                   \
        _Pragma("unroll")                                                      \
        for (int it = 0; it < 4; ++it)                                         \
            _Pragma("unroll")                                                  \
            for (int j = 0; j < 4; ++j) {                                      \
                int g = gb_ + 4 * it + j;                                      \
                VV[it][j] = (g < TT) ? vsl[(size_t)g * FF + f] : 0.f;          \
            }                                                                  \
    }                                                                          \
} while (0)

#define SCAT_A_(AQ, AE) do {                                                   \
    _Pragma("unroll")                                                          \
    for (int it = 0; it < 4; ++it) {                                           \
        int lin = tid + it * 256;                                              \
        if (lin < TILE * 15) {                                                 \
            int R = lin / 15, j = lin - R * 15;                                \
            int r0 = (4 - (R & 3)) & 3;                                        \
            int rq = r0 + 4 * j;                                               \
            float4 q = AQ[it];                                                 \
            uint2 pw; pw.x = pk2(q.x, q.y); pw.y = pk2(q.z, q.w);              \
            *(uint2*)&sa[R * SA_S + (R & 31) + rq] = pw;                       \
        }                                                                      \
    }                                                                          \
    _Pragma("unroll")                                                          \
    for (int it = 0; it < 2; ++it) {                                           \
        int lin = tid + it * 256;                                              \
        if (lin < TILE * 5) {                                                  \
            int R = lin / 5, e = lin - R * 5;                                  \
            int r0 = (4 - (R & 3)) & 3;                                        \
            int r = (e < r0) ? e : 60 + e;                                     \
            sa[R * SA_S + (R & 31) + r] = f2bf(AE[it]);                        \
        }                                                                      \
    }                                                                          \
} while (0)

#define SCAT_V_(VV, S0) do {                                                   \
    const int cb_ = (S0) + 16 * wv;                                            \
    _Pragma("unroll")                                                          \
    for (int it = 0; it < 4; ++it) {                                           \
        uint2 pw; pw.x = pk2(VV[it][0], VV[it][1]);                            \
        pw.y = pk2(VV[it][2], VV[it][3]);                                      \
        *(uint2*)&sv[f * SV_S + ((cb_ + 4 * it) & RM)] = pw;                   \
    }                                                                          \
} while (0)

#define COMPUTE_(TROW) do {                                                    \
    const int cbase_ = ((TROW) - 32) & RM;                                     \
    f32x16 acc = {};                                                           \
    _Pragma("unroll")                                                          \
    for (int kb = 0; kb < 6; ++kb) {                                           \
        const int cp = kb * 16 + hi * 8;                                       \
        bf16x8 af = *(const bf16x8*)&sa[Rw * SA_S + cp];                       \
        bf16x8 bv = *(const bf16x8*)&sv[(32 * wc + n) * SV_S                   \
                                        + ((cbase_ + 32 * wr + cp) & RM)];     \
        acc = __builtin_amdgcn_mfma_f32_32x32x16_bf16(af, bv, acc, 0, 0, 0);   \
    }                                                                          \
    float* op = out + obase + (size_t)((TROW) + 32 * wr) * FF + 32 * wc;       \
    _Pragma("unroll")                                                          \
    for (int reg = 0; reg < 16; ++reg) {                                       \
        int row = (reg & 3) + 8 * (reg >> 2) + 4 * hi;                         \
        __builtin_nontemporal_store(acc[reg], &op[row * FF + n]);              \
    }                                                                          \
} while (0)

    float4 aqA[4], aqB[4];
    float  aeA[2], aeB[2];
    float  vvA[4][4], vvB[4][4];

    // ---- prologue: tile0 a + tile0 full 128-row v window; tile1 a + segment ----
    ISSUE_A_(aqA, aeA, T0);
    {
        float pv[8][4];
        const int gb = T0 - 32 + 32 * wv;
        if (T0 >= 32) {
            #pragma unroll
            for (int it = 0; it < 8; ++it)
                #pragma unroll
                for (int j = 0; j < 4; ++j)
                    pv[it][j] = vsl[(size_t)(gb + 4 * it + j) * FF + f];
        } else {
            #pragma unroll
            for (int it = 0; it < 8; ++it)
                #pragma unroll
                for (int j = 0; j < 4; ++j) {
                    int g = gb + 4 * it + j;
                    pv[it][j] = (g >= 0) ? vsl[(size_t)g * FF + f] : 0.f;
                }
        }
        #pragma unroll
        for (int it = 0; it < 8; ++it) {
            uint2 pw; pw.x = pk2(pv[it][0], pv[it][1]);
            pw.y = pk2(pv[it][2], pv[it][3]);
            *(uint2*)&sv[f * SV_S + ((gb + 4 * it) & RM)] = pw;
        }
    }
    ISSUE_A_(aqB, aeB, T0 + 64);
    ISSUE_V_(vvB, T0 + 96);
    BAR();

    // ---- tile 0 (set A) ----
    SCAT_A_(aqA, aeA);
    BAR();
    ISSUE_A_(aqA, aeA, T0 + 128);      // depth-2: tile 2
    ISSUE_V_(vvA, T0 + 160);
    COMPUTE_(T0);
    BAR();

    // ---- tile 1 (set B) ----
    SCAT_A_(aqB, aeB);
    SCAT_V_(vvB, T0 + 96);
    BAR();
    ISSUE_A_(aqB, aeB, T0 + 192);      // depth-2: tile 3
    ISSUE_V_(vvB, T0 + 224);
    COMPUTE_(T0 + 64);
    BAR();

    // ---- tile 2 (set A) ----
    SCAT_A_(aqA, aeA);
    SCAT_V_(vvA, T0 + 160);
    BAR();
    COMPUTE_(T0 + 128);
    BAR();

    // ---- tile 3 (set B) ----
    SCAT_A_(aqB, aeB);
    SCAT_V_(vvB, T0 + 224);
    BAR();
    COMPUTE_(T0 + 192);
}

extern "C" void kernel_launch(void* const* d_in, const int* in_sizes, int n_in,
                              void* d_out, int out_size, void* d_ws, size_t ws_size,
                              hipStream_t stream) {
    const float* a = (const float*)d_in[0];
    const float* v = (const float*)d_in[1];
    float* out = (float*)d_out;

    const int BH = in_sizes[1] / (TT * FF);          // 128
    const int grid = BH * (TT / TILE) / NTPB;        // 2048 blocks

    unfold_mfma<<<grid, 256, 0, stream>>>(a, v, out);
}

// Round 9
// 76.406 us; speedup vs baseline: 3.7578x; 3.7578x over previous
//
#include <hip/hip_runtime.h>

// out[b,h,t,f] = sum_{r=0..64} a[b,h,t,r] * v[b,h, t+r-32, f]  (zero-padded in t)
// B=8 H=16 T=4096 F=64 R=65, fp32 in/out. bf16 MFMA (absmax 0.25 vs thr 1.0).
//
// Round 9 = round 6 (75.5us, 64 VGPR, no spills) with EXACTLY one change:
// the two in-loop __syncthreads() -> lgkmcnt-only barriers. __syncthreads()
// emits s_waitcnt vmcnt(0), which drained BOTH the next tile's prefetched
// global loads AND the 16 nontemporal store retirements at every tile (guide
// §5 m97). Round 8 proved the barrier swap is correct but buried it under
// register spills (depth-2 A/B sets at bounds(256,5): WRITE 131->733MB).
// Here register pressure is identical to round 6 -> no spill possible.

#define TT 4096
#define RRR 65
#define FF 64
#define TILE 64
#define SA_S 100     // bf16 row stride: 200B rows -> 2-way (free) on A b128 reads
#define SV_S 132     // bf16 row stride: 264B rows -> 2-way (free) on B b128 reads
#define NTPB 8       // tiles per block (8 | 64 -> bh constant per block)

typedef short bf16x8 __attribute__((ext_vector_type(8)));
typedef float f32x16 __attribute__((ext_vector_type(16)));

__device__ __forceinline__ unsigned short f2bf(float x) {
    unsigned int u = __float_as_uint(x);
    u += 0x7fff + ((u >> 16) & 1);            // RNE
    return (unsigned short)(u >> 16);
}
__device__ __forceinline__ unsigned pk2(float lo, float hi) {
    return (unsigned)f2bf(lo) | ((unsigned)f2bf(hi) << 16);
}

// Barrier with LDS-only drain: global loads/stores stay in flight (no vmcnt!).
#define BAR() do {                                                             \
    asm volatile("s_waitcnt lgkmcnt(0)" ::: "memory");                         \
    __builtin_amdgcn_sched_barrier(0);                                         \
    __builtin_amdgcn_s_barrier();                                              \
    __builtin_amdgcn_sched_barrier(0);                                         \
} while (0)

__global__ __launch_bounds__(256, 4)
void unfold_mfma(const float* __restrict__ a, const float* __restrict__ v,
                 float* __restrict__ out) {
    __shared__ __align__(16) unsigned short sa[TILE * SA_S];  // 12800 B
    __shared__ __align__(16) unsigned short sv[FF * SV_S];    // 16896 B

    const int tid = threadIdx.x;
    const int f   = tid & 63;
    const int wv  = tid >> 6;

    const int bh = blockIdx.x >> 3;                 // 8 blocks per (b,h)
    const float* vsl = v + (size_t)bh * TT * FF;
    const size_t obase = (size_t)bh * TT * FF;

    // ---- one-time zero-prefill of sa (band complement stays 0 across tiles) ----
    {
        uint4 z = make_uint4(0, 0, 0, 0);
        uint4* sp = (uint4*)sa;
        #pragma unroll
        for (int it = 0; it < 4; ++it) {
            int lin = tid + it * 256;
            if (lin < (TILE * SA_S) / 8) sp[lin] = z;
        }
    }

    float4 aq[4];
    float  ae[2];
    float  vv[8][4];

    int t0 = ((blockIdx.x & 7) * NTPB) << 6;
    const float* arow = a + ((size_t)bh * TT + t0) * RRR;

    // ---- load issue: a quads (aligned), a edges, v slab (interior fast path) ----
#define ISSUE_LOADS() do {                                                     \
    _Pragma("unroll")                                                          \
    for (int it = 0; it < 4; ++it) {                                           \
        int lin = tid + it * 256;                                              \
        if (lin < TILE * 15) {                                                 \
            int R = lin / 15, j = lin - R * 15;                                \
            int r0 = (4 - (R & 3)) & 3;                                        \
            aq[it] = *(const float4*)(arow + (size_t)R * RRR + r0 + 4 * j);    \
        }                                                                      \
    }                                                                          \
    _Pragma("unroll")                                                          \
    for (int it = 0; it < 2; ++it) {                                           \
        int lin = tid + it * 256;                                              \
        if (lin < TILE * 5) {                                                  \
            int R = lin / 5, e = lin - R * 5;                                  \
            int r0 = (4 - (R & 3)) & 3;                                        \
            int r = (e < r0) ? e : 60 + e;                                     \
            ae[it] = arow[(size_t)R * RRR + r];                                \
        }                                                                      \
    }                                                                          \
    {                                                                          \
        const int gb = t0 - 32 + 32 * wv;                                      \
        if (t0 >= 32 && t0 + 96 <= TT) {                                       \
            _Pragma("unroll")                                                  \
            for (int it = 0; it < 8; ++it)                                     \
                _Pragma("unroll")                                              \
                for (int j = 0; j < 4; ++j)                                    \
                    vv[it][j] = vsl[(size_t)(gb + 4 * it + j) * FF + f];       \
        } else {                                                               \
            _Pragma("unroll")                                                  \
            for (int it = 0; it < 8; ++it)                                     \
                _Pragma("unroll")                                              \
                for (int j = 0; j < 4; ++j) {                                  \
                    int g = gb + 4 * it + j;                                   \
                    vv[it][j] = (g >= 0 && g < TT)                             \
                                ? vsl[(size_t)g * FF + f] : 0.f;               \
                }                                                              \
        }                                                                      \
    }                                                                          \
} while (0)

    // ---- convert + LDS scatter of the staged registers ----
#define SCATTER() do {                                                         \
    _Pragma("unroll")                                                          \
    for (int it = 0; it < 4; ++it) {                                           \
        int lin = tid + it * 256;                                              \
        if (lin < TILE * 15) {                                                 \
            int R = lin / 15, j = lin - R * 15;                                \
            int r0 = (4 - (R & 3)) & 3;                                        \
            int rq = r0 + 4 * j;                                               \
            float4 q = aq[it];                                                 \
            uint2 pw; pw.x = pk2(q.x, q.y); pw.y = pk2(q.z, q.w);              \
            *(uint2*)&sa[R * SA_S + (R & 31) + rq] = pw;                       \
        }                                                                      \
    }                                                                          \
    _Pragma("unroll")                                                          \
    for (int it = 0; it < 2; ++it) {                                           \
        int lin = tid + it * 256;                                              \
        if (lin < TILE * 5) {                                                  \
            int R = lin / 5, e = lin - R * 5;                                  \
            int r0 = (4 - (R & 3)) & 3;                                        \
            int r = (e < r0) ? e : 60 + e;                                     \
            sa[R * SA_S + (R & 31) + r] = f2bf(ae[it]);                        \
        }                                                                      \
    }                                                                          \
    _Pragma("unroll")                                                          \
    for (int it = 0; it < 8; ++it) {                                           \
        uint2 pw; pw.x = pk2(vv[it][0], vv[it][1]);                            \
        pw.y = pk2(vv[it][2], vv[it][3]);                                      \
        *(uint2*)&sv[f * SV_S + 32 * wv + 4 * it] = pw;                        \
    }                                                                          \
} while (0)

    ISSUE_LOADS();
    __syncthreads();   // prologue: full drain once is fine

    const int n  = f & 31;
    const int hi = f >> 5;
    const int wr = wv >> 1;
    const int wc = wv & 1;
    const int Rw = 32 * wr + n;

    #pragma unroll 1
    for (int i = 0; i < NTPB; ++i) {
        SCATTER();
        const int cur_t0 = t0;
        BAR();                        // LDS-only drain (was __syncthreads)

        if (i + 1 < NTPB) {
            t0 += TILE;
            arow = a + ((size_t)bh * TT + t0) * RRR;
            ISSUE_LOADS();           // overlaps compute+stores below
        }

        // ---- MFMA: wave (wr,wc) -> rows [cur_t0+32wr,+32), cols [32wc,+32) ----
        f32x16 acc = {};
        #pragma unroll
        for (int kb = 0; kb < 6; ++kb) {
            const int cp = kb * 16 + hi * 8;
            bf16x8 af = *(const bf16x8*)&sa[Rw * SA_S + cp];
            bf16x8 bv = *(const bf16x8*)&sv[(32 * wc + n) * SV_S + (32 * wr + cp)];
            acc = __builtin_amdgcn_mfma_f32_32x32x16_bf16(af, bv, acc, 0, 0, 0);
        }

        // C/D: col = lane&31, row = (reg&3) + 8*(reg>>2) + 4*(lane>>5)
        float* op = out + obase + (size_t)(cur_t0 + 32 * wr) * FF + 32 * wc;
        #pragma unroll
        for (int reg = 0; reg < 16; ++reg) {
            int row = (reg & 3) + 8 * (reg >> 2) + 4 * hi;
            __builtin_nontemporal_store(acc[reg], &op[row * FF + n]);
        }
        BAR();                        // LDS free for next scatter (no vmcnt drain)
    }
}

extern "C" void kernel_launch(void* const* d_in, const int* in_sizes, int n_in,
                              void* d_out, int out_size, void* d_ws, size_t ws_size,
                              hipStream_t stream) {
    const float* a = (const float*)d_in[0];
    const float* v = (const float*)d_in[1];
    float* out = (float*)d_out;

    const int BH = in_sizes[1] / (TT * FF);          // 128
    const int grid = BH * (TT / TILE) / NTPB;        // 1024 blocks

    unfold_mfma<<<grid, 256, 0, stream>>>(a, v, out);
}